// Round 1
// baseline (4142.183 us; speedup 1.0000x reference)
//
#include <hip/hip_runtime.h>
#include <hip/hip_bf16.h>
#include <math.h>

// ---------------------------------------------------------------------------
// PointNet++ Set Abstraction: FPS -> kNN -> grouped MLP(6->32->32->64) with
// BatchNorm(training stats) + ReLU -> max over K.
// B=8, N=8192, S=2048, K=32. All fp32.
//
// d_out layout (floats): new_xyz [8,3,2048] | new_points [8,64,2048] | fps_idx [8,2048]
// ---------------------------------------------------------------------------

#define NB 8
#define NN 8192
#define NS 2048
#define NK 32

// ---------------- prep: transpose to [B,N,4] with w = |p|^2 -----------------
__global__ __launch_bounds__(256) void prep_kernel(const float* __restrict__ xyz,
                                                   const float* __restrict__ pts,
                                                   float4* __restrict__ xyz4,
                                                   float4* __restrict__ pts4) {
  int g = blockIdx.x * 256 + threadIdx.x;      // 65536 = B*N
  int b = g >> 13, n = g & 8191;
  const float* xb = xyz + b * 3 * NN;
  float x = xb[n], y = xb[NN + n], z = xb[2 * NN + n];
  xyz4[g] = make_float4(x, y, z, fmaf(x, x, fmaf(y, y, z * z)));
  const float* pb = pts + b * 3 * NN;
  pts4[g] = make_float4(pb[n], pb[NN + n], pb[2 * NN + n], 0.f);
}

// ---------------- FPS: one block per batch, exact numpy-matching ------------
__global__ __launch_bounds__(1024) void fps_kernel(const float4* __restrict__ xyz4,
                                                   float* __restrict__ out_nxyz,
                                                   float* __restrict__ out_fps,
                                                   float4* __restrict__ nxyz4) {
  int b = blockIdx.x, tid = threadIdx.x;
  int lane = tid & 63, wid = tid >> 6;
  __shared__ float4 cslot;
  __shared__ unsigned long long wslot[16];

  // thread owns contiguous points [tid*8, tid*8+8)
  float4 p[8];
  float dist[8];
#pragma unroll
  for (int j = 0; j < 8; ++j) {
    p[j] = xyz4[b * NN + (tid << 3) + j];
    dist[j] = 1e10f;
  }
  if (tid == 0) {
    cslot = p[0];
    nxyz4[b * NS] = p[0];
    out_nxyz[b * 3 * NS] = p[0].x;
    out_nxyz[b * 3 * NS + NS] = p[0].y;
    out_nxyz[b * 3 * NS + 2 * NS] = p[0].z;
    out_fps[b * NS] = 0.f;
  }
  __syncthreads();

  for (int s = 1; s < NS; ++s) {
    float4 c = cslot;
    // exact (no-FMA, left-to-right) distance + running min, matches numpy
#pragma unroll
    for (int j = 0; j < 8; ++j) {
      float dx = __fsub_rn(p[j].x, c.x);
      float dy = __fsub_rn(p[j].y, c.y);
      float dz = __fsub_rn(p[j].z, c.z);
      float d = __fadd_rn(__fadd_rn(__fmul_rn(dx, dx), __fmul_rn(dy, dy)), __fmul_rn(dz, dz));
      dist[j] = fminf(dist[j], d);
    }
    float lmax = dist[0];
#pragma unroll
    for (int j = 1; j < 8; ++j) lmax = fmaxf(lmax, dist[j]);

    // wave max (f32 butterfly); tie -> lowest lane = lowest global idx (exact)
    float wmax = lmax;
#pragma unroll
    for (int d = 1; d < 64; d <<= 1) wmax = fmaxf(wmax, __shfl_xor(wmax, d));
    unsigned long long ball = __ballot(lmax == wmax);
    int wlane = __ffsll(ball) - 1;
    if (lane == wlane) {
      int j = 7;
#pragma unroll
      for (int t = 6; t >= 0; --t)
        if (dist[t] == lmax) j = t;  // smallest local j on ties
      int gid = (tid << 3) | j;
      wslot[wid] = (((unsigned long long)__float_as_uint(lmax)) << 32) |
                   (unsigned)(8191 - gid);  // u64-max => max val, then min gid
    }
    __syncthreads();

    // every wave redundantly reduces the 16 wave-slots (saves a barrier)
    unsigned long long v = wslot[lane & 15];
#pragma unroll
    for (int d = 1; d < 16; d <<= 1) {
      unsigned long long o = __shfl_xor(v, d);
      v = (o > v) ? o : v;
    }
    int gid = 8191 - (int)(unsigned)(v & 0xFFFFFFFFull);

    if (tid == (gid >> 3)) {  // owner broadcasts centroid coords + writes outputs
      int j = gid & 7;
      float4 c2 = p[0];
#pragma unroll
      for (int t = 1; t < 8; ++t)
        if (j == t) c2 = p[t];
      cslot = c2;
      nxyz4[b * NS + s] = c2;
      out_nxyz[b * 3 * NS + s] = c2.x;
      out_nxyz[b * 3 * NS + NS + s] = c2.y;
      out_nxyz[b * 3 * NS + 2 * NS + s] = c2.z;
      out_fps[b * NS + s] = (float)gid;
    }
    __syncthreads();
  }
}

// ---------------- kNN: idx packed into low 13 mantissa bits -----------------
__device__ __forceinline__ void insert32(float (&a)[32], float f) {
  // sorted ascending; keep 32 smallest. new[i] = min(a[i], max(a[i-1], f))
#pragma unroll
  for (int i = 31; i >= 1; --i) a[i] = fminf(a[i], fmaxf(a[i - 1], f));
  a[0] = fminf(a[0], f);
}

__global__ __launch_bounds__(256) void knn_kernel(const float4* __restrict__ xyz4,
                                                  const float4* __restrict__ nxyz4,
                                                  int* __restrict__ knn) {
  __shared__ float lbuf[256][33];  // +1 pad: conflict-free
  int b = blockIdx.x >> 5, tile = blockIdx.x & 31;
  int tid = threadIdx.x;
  int q = tid & 63, chunk = tid >> 6;  // 64 queries x 4 ref-chunks
  float4 Q = nxyz4[b * NS + tile * 64 + q];
  float qq = Q.w;
  float mx = -2.f * Q.x, my = -2.f * Q.y, mz = -2.f * Q.z;
  float arr[32];
#pragma unroll
  for (int i = 0; i < 32; ++i) arr[i] = __uint_as_float(0x7f7fffffu);

  const float4* refs = xyz4 + b * NN + chunk * 2048;
  int rbase = chunk * 2048;
  for (int r = 0; r < 2048; ++r) {
    float4 R = refs[r];  // uniform per wave -> scalar load
    float d = fmaf(R.x, mx, fmaf(R.y, my, fmaf(R.z, mz, R.w + qq)));
    d = fmaxf(d, 0.f);
    float f = __uint_as_float((__float_as_uint(d) & 0xFFFFE000u) | (unsigned)(rbase + r));
    if (f < arr[31]) insert32(arr, f);
  }
#pragma unroll
  for (int i = 0; i < 32; ++i) lbuf[tid][i] = arr[i];
  __syncthreads();
  if (tid < 64) {  // merge 4 chunks for query tid
    for (int c = 1; c < 4; ++c)
      for (int i = 0; i < 32; ++i) {
        float f = lbuf[c * 64 + tid][i];
        if (f < arr[31]) insert32(arr, f);
      }
    int base = (b * NS + tile * 64 + tid) * NK;
#pragma unroll
    for (int i = 0; i < 32; ++i) knn[base + i] = (int)(__float_as_uint(arr[i]) & 0x1FFFu);
  }
}

// ---------------- MLP passes (recompute; BN needs global stats) -------------
// STAGE 0: y0 stats | 1: ->y1 stats | 2: ->y2 stats | 3: full + maxK + out
template <int STAGE>
__global__ __launch_bounds__(256) void mlp_kernel(
    const float4* __restrict__ xyz4, const float4* __restrict__ pts4,
    const float4* __restrict__ nxyz4, const int* __restrict__ knn,
    const float* __restrict__ w0, const float* __restrict__ w1,
    const float* __restrict__ w2, const float* __restrict__ ab,
    float* __restrict__ partials, float* __restrict__ out_np) {
  constexpr int C = (STAGE == 2) ? 64 : 32;              // stats channels
  constexpr int SM = (STAGE == 3) ? 8 * 64 * 32 : 512;   // floats
  __shared__ float smem[SM];
  int blk = blockIdx.x;
  int b = blk >> 6, s0 = (blk & 63) * 32;
  int tid = threadIdx.x, sl = tid & 31, ksec = tid >> 5;
  int lane = tid & 63, wid = tid >> 6;
  int s = s0 + sl;
  float4 Q = nxyz4[b * NS + s];
  const float4* xb = xyz4 + b * NN;
  const float4* pb = pts4 + b * NN;
  const int* kb = knn + (b * NS + s) * NK + ksec * 4;

  float acc1[(STAGE == 3) ? 64 : C];
  float acc2[(STAGE == 3) ? 1 : C];
  if constexpr (STAGE == 3) {
#pragma unroll
    for (int o = 0; o < 64; ++o) acc1[o] = -3.4e38f;
  } else {
#pragma unroll
    for (int o = 0; o < C; ++o) { acc1[o] = 0.f; acc2[o] = 0.f; }
  }

  for (int kk = 0; kk < 4; ++kk) {
    int nid = kb[kk];
    float4 R = xb[nid];
    float4 P = pb[nid];
    float x0[6] = {R.x - Q.x, R.y - Q.y, R.z - Q.z, P.x, P.y, P.z};
    float h[32];
#pragma unroll
    for (int o = 0; o < 32; ++o) {
      float a = w0[o * 6] * x0[0];
#pragma unroll
      for (int c = 1; c < 6; ++c) a = fmaf(w0[o * 6 + c], x0[c], a);
      h[o] = a;
    }
    if constexpr (STAGE == 0) {
#pragma unroll
      for (int o = 0; o < 32; ++o) { acc1[o] += h[o]; acc2[o] = fmaf(h[o], h[o], acc2[o]); }
    } else {
#pragma unroll
      for (int o = 0; o < 32; ++o) h[o] = fmaxf(fmaf(h[o], ab[o], ab[64 + o]), 0.f);
      float h1[32];
#pragma unroll
      for (int o = 0; o < 32; ++o) {
        float a = 0.f;
#pragma unroll
        for (int i = 0; i < 32; ++i) a = fmaf(w1[o * 32 + i], h[i], a);
        h1[o] = a;
      }
      if constexpr (STAGE == 1) {
#pragma unroll
        for (int o = 0; o < 32; ++o) { acc1[o] += h1[o]; acc2[o] = fmaf(h1[o], h1[o], acc2[o]); }
      } else {
#pragma unroll
        for (int o = 0; o < 32; ++o) h1[o] = fmaxf(fmaf(h1[o], ab[128 + o], ab[192 + o]), 0.f);
#pragma unroll
        for (int o = 0; o < 64; ++o) {
          float a = 0.f;
#pragma unroll
          for (int i = 0; i < 32; ++i) a = fmaf(w2[o * 32 + i], h1[i], a);
          if constexpr (STAGE == 2) {
            acc1[o] += a;
            acc2[o] = fmaf(a, a, acc2[o]);
          } else {
            acc1[o] = fmaxf(acc1[o], fmaxf(fmaf(a, ab[256 + o], ab[320 + o]), 0.f));
          }
        }
      }
    }
  }

  if constexpr (STAGE < 3) {
    // wave shuffle reduce -> per-wave slot -> per-block partial
#pragma unroll
    for (int o = 0; o < C; ++o) {
      float v1 = acc1[o], v2 = acc2[o];
#pragma unroll
      for (int d = 1; d < 64; d <<= 1) { v1 += __shfl_xor(v1, d); v2 += __shfl_xor(v2, d); }
      acc1[o] = v1; acc2[o] = v2;
    }
    if (lane == 0) {
#pragma unroll
      for (int o = 0; o < C; ++o) {
        smem[wid * 2 * C + o] = acc1[o];
        smem[wid * 2 * C + C + o] = acc2[o];
      }
    }
    __syncthreads();
    if (tid < 2 * C) {
      float v = smem[tid] + smem[2 * C + tid] + smem[4 * C + tid] + smem[6 * C + tid];
      partials[blk * 128 + tid] = v;
    }
  } else {
#pragma unroll
    for (int o = 0; o < 64; ++o) smem[ksec * 2048 + o * 32 + sl] = acc1[o];
    __syncthreads();
#pragma unroll
    for (int i = 0; i < 8; ++i) {
      int e = i * 256 + tid;
      int ch = e >> 5, ss = e & 31;
      float v = smem[ch * 32 + ss];
#pragma unroll
      for (int ks = 1; ks < 8; ++ks) v = fmaxf(v, smem[ks * 2048 + ch * 32 + ss]);
      out_np[b * 64 * NS + ch * NS + s0 + ss] = v;
    }
  }
}

__global__ __launch_bounds__(256) void finalize_kernel(const float* __restrict__ partials,
                                                       const float* __restrict__ g,
                                                       const float* __restrict__ bt,
                                                       float* __restrict__ ab, int C) {
  __shared__ float sm[256];
  int tid = threadIdx.x;
  int ch = tid & 127, half = tid >> 7;
  float acc = 0.f;
  if (ch < 2 * C) {
    const float* p = partials + half * 256 * 128 + ch;
    for (int i = 0; i < 256; ++i) acc += p[i * 128];
  }
  sm[half * 128 + ch] = acc;
  __syncthreads();
  if (tid < C) {
    float s1 = sm[tid] + sm[128 + tid];
    float s2 = sm[C + tid] + sm[128 + C + tid];
    const float ninv = 1.0f / 524288.0f;  // B*S*K
    float mean = s1 * ninv;
    float var = s2 * ninv - mean * mean;
    float inv = 1.0f / sqrtf(var + 1e-5f);
    float a = g[tid] * inv;
    ab[tid] = a;
    ab[64 + tid] = bt[tid] - mean * a;
  }
}

// ---------------------------------------------------------------------------
extern "C" void kernel_launch(void* const* d_in, const int* in_sizes, int n_in,
                              void* d_out, int out_size, void* d_ws, size_t ws_size,
                              hipStream_t stream) {
  const float* xyz = (const float*)d_in[0];
  const float* pts = (const float*)d_in[1];
  const float* w0 = (const float*)d_in[2];
  const float* g0 = (const float*)d_in[3];
  const float* b0 = (const float*)d_in[4];
  const float* w1 = (const float*)d_in[5];
  const float* g1 = (const float*)d_in[6];
  const float* b1 = (const float*)d_in[7];
  const float* w2 = (const float*)d_in[8];
  const float* g2 = (const float*)d_in[9];
  const float* b2 = (const float*)d_in[10];
  float* out = (float*)d_out;
  float* ws = (float*)d_ws;

  float4* xyz4 = (float4*)ws;                  // 262144 floats
  float4* pts4 = (float4*)(ws + 262144);       // 262144
  float4* nxyz4 = (float4*)(ws + 524288);      // 65536
  int* knn = (int*)(ws + 589824);              // 524288 ints
  float* partials = ws + 1114112;              // 3 * 65536
  float* ab = ws + 1310720;                    // 384
  float* out_np = out + 49152;                 // new_points [8,64,2048]
  float* out_fps = out + 1097728;              // fps_idx as float [8,2048]

  prep_kernel<<<256, 256, 0, stream>>>(xyz, pts, xyz4, pts4);
  fps_kernel<<<NB, 1024, 0, stream>>>(xyz4, out, out_fps, nxyz4);
  knn_kernel<<<256, 256, 0, stream>>>(xyz4, nxyz4, knn);

  mlp_kernel<0><<<512, 256, 0, stream>>>(xyz4, pts4, nxyz4, knn, w0, w1, w2, ab, partials, nullptr);
  finalize_kernel<<<1, 256, 0, stream>>>(partials, g0, b0, ab, 32);
  mlp_kernel<1><<<512, 256, 0, stream>>>(xyz4, pts4, nxyz4, knn, w0, w1, w2, ab, partials + 65536, nullptr);
  finalize_kernel<<<1, 256, 0, stream>>>(partials + 65536, g1, b1, ab + 128, 32);
  mlp_kernel<2><<<512, 256, 0, stream>>>(xyz4, pts4, nxyz4, knn, w0, w1, w2, ab, partials + 131072, nullptr);
  finalize_kernel<<<1, 256, 0, stream>>>(partials + 131072, g2, b2, ab + 256, 64);
  mlp_kernel<3><<<512, 256, 0, stream>>>(xyz4, pts4, nxyz4, knn, w0, w1, w2, ab, nullptr, out_np);
}

// Round 2
// 3085.362 us; speedup vs baseline: 1.3425x; 1.3425x over previous
//
#include <hip/hip_runtime.h>
#include <hip/hip_bf16.h>
#include <math.h>

// ---------------------------------------------------------------------------
// PointNet++ Set Abstraction: FPS -> kNN -> grouped MLP(6->32->32->64) with
// BatchNorm(training stats) + ReLU -> max over K.
// B=8, N=8192, S=2048, K=32. All fp32.
//
// d_out layout (floats): new_xyz [8,3,2048] | new_points [8,64,2048] | fps_idx [8,2048]
// ---------------------------------------------------------------------------

#define NB 8
#define NN 8192
#define NS 2048
#define NK 32

// ---------------- prep: transpose to [B,N,4] with w = |p|^2 -----------------
__global__ __launch_bounds__(256) void prep_kernel(const float* __restrict__ xyz,
                                                   const float* __restrict__ pts,
                                                   float4* __restrict__ xyz4,
                                                   float4* __restrict__ pts4) {
  int g = blockIdx.x * 256 + threadIdx.x;      // 65536 = B*N
  int b = g >> 13, n = g & 8191;
  const float* xb = xyz + b * 3 * NN;
  float x = xb[n], y = xb[NN + n], z = xb[2 * NN + n];
  xyz4[g] = make_float4(x, y, z, fmaf(x, x, fmaf(y, y, z * z)));
  const float* pb = pts + b * 3 * NN;
  pts4[g] = make_float4(pb[n], pb[NN + n], pb[2 * NN + n], 0.f);
}

// ---------------- FPS: one block/batch, DPP wave-reduce, 1 barrier/iter -----
template <int CTRL>
__device__ __forceinline__ float dpp_max(float v) {
  int o = __builtin_amdgcn_update_dpp(__float_as_int(v), __float_as_int(v),
                                      CTRL, 0xf, 0xf, false);
  return fmaxf(v, __int_as_float(o));
}

__global__ __launch_bounds__(256, 1) void fps_kernel(const float4* __restrict__ xyz4,
                                                     float* __restrict__ out_nxyz,
                                                     float* __restrict__ out_fps,
                                                     float4* __restrict__ nxyz4) {
  int b = blockIdx.x, tid = threadIdx.x;
  int lane = tid & 63, wid = tid >> 6;
  __shared__ unsigned long long wslot[2][4];
  const float4* xb = xyz4 + b * NN;

  // thread owns contiguous points [tid*32, tid*32+32): lane order == gid order
  float px[32], py[32], pz[32], dist[32];
#pragma unroll
  for (int j = 0; j < 32; ++j) {
    float4 t = xb[(tid << 5) + j];
    px[j] = t.x; py[j] = t.y; pz[j] = t.z;
    dist[j] = 1e10f;
  }
  float4 c0 = xb[0];
  float cx = c0.x, cy = c0.y, cz = c0.z;
  if (tid == 0) {
    nxyz4[b * NS] = c0;
    out_nxyz[b * 3 * NS] = c0.x;
    out_nxyz[b * 3 * NS + NS] = c0.y;
    out_nxyz[b * 3 * NS + 2 * NS] = c0.z;
    out_fps[b * NS] = 0.f;
  }

  for (int s = 1; s < NS; ++s) {
    // exact (no-FMA, left-to-right) distance, running min, fused argmax track
    float best = -1.0f;
    int bj = 0;
#pragma unroll
    for (int j = 0; j < 32; ++j) {
      float dx = __fsub_rn(px[j], cx);
      float dy = __fsub_rn(py[j], cy);
      float dz = __fsub_rn(pz[j], cz);
      float d = __fadd_rn(__fadd_rn(__fmul_rn(dx, dx), __fmul_rn(dy, dy)),
                          __fmul_rn(dz, dz));
      d = fminf(dist[j], d);
      dist[j] = d;
      bool gt = d > best;           // strict >: keeps smallest j on ties
      best = gt ? d : best;
      bj = gt ? j : bj;
    }

    // wave64 max via DPP (all VALU, no LDS): result valid in lane 63
    float m = best;
    m = dpp_max<0x111>(m);  // row_shr:1
    m = dpp_max<0x112>(m);  // row_shr:2
    m = dpp_max<0x114>(m);  // row_shr:4
    m = dpp_max<0x118>(m);  // row_shr:8
    m = dpp_max<0x142>(m);  // row_bcast:15
    m = dpp_max<0x143>(m);  // row_bcast:31
    float wmax = __int_as_float(__builtin_amdgcn_readlane(__float_as_int(m), 63));

    unsigned long long bl = __ballot(best == wmax);
    int l0 = __ffsll((unsigned long long)bl) - 1;   // lowest lane = lowest gid
    int gcand = (tid << 5) + bj;
    int gw = __builtin_amdgcn_readlane(gcand, l0);

    if (lane == 0)
      wslot[s & 1][wid] = (((unsigned long long)__float_as_uint(wmax)) << 32) |
                          (unsigned)(8191 - gw);  // u64-max => max val, min gid
    __syncthreads();

    unsigned long long v0 = wslot[s & 1][0], v1 = wslot[s & 1][1];
    unsigned long long v2 = wslot[s & 1][2], v3 = wslot[s & 1][3];
    unsigned long long va = v0 > v1 ? v0 : v1;
    unsigned long long vb = v2 > v3 ? v2 : v3;
    unsigned long long vm = va > vb ? va : vb;
    int gid = 8191 - (int)(unsigned)(vm & 0xFFFFFFFFull);

    float4 c = xb[gid];  // uniform address: one L1/L2 request, broadcast
    cx = c.x; cy = c.y; cz = c.z;
    if (tid == 0) {
      nxyz4[b * NS + s] = c;
      out_nxyz[b * 3 * NS + s] = c.x;
      out_nxyz[b * 3 * NS + NS + s] = c.y;
      out_nxyz[b * 3 * NS + 2 * NS + s] = c.z;
      out_fps[b * NS + s] = (float)gid;
    }
    // no second barrier: parity buffer wslot[s&1]; iter s+2's writes can only
    // happen after barrier s+1, which requires all threads done reading iter s
  }
}

// ---------------- kNN: idx packed into low 13 mantissa bits -----------------
__device__ __forceinline__ void insert32(float (&a)[32], float f) {
  // sorted ascending; keep 32 smallest. new[i] = min(a[i], max(a[i-1], f))
#pragma unroll
  for (int i = 31; i >= 1; --i) a[i] = fminf(a[i], fmaxf(a[i - 1], f));
  a[0] = fminf(a[0], f);
}

__global__ __launch_bounds__(256) void knn_kernel(const float4* __restrict__ xyz4,
                                                  const float4* __restrict__ nxyz4,
                                                  int* __restrict__ knn) {
  __shared__ float lbuf[256][33];  // +1 pad: conflict-free
  int b = blockIdx.x >> 5, tile = blockIdx.x & 31;
  int tid = threadIdx.x;
  int q = tid & 63, chunk = tid >> 6;  // 64 queries x 4 ref-chunks
  float4 Q = nxyz4[b * NS + tile * 64 + q];
  float qq = Q.w;
  float mx = -2.f * Q.x, my = -2.f * Q.y, mz = -2.f * Q.z;
  float arr[32];
#pragma unroll
  for (int i = 0; i < 32; ++i) arr[i] = __uint_as_float(0x7f7fffffu);

  const float4* refs = xyz4 + b * NN + chunk * 2048;
  int rbase = chunk * 2048;
  for (int r = 0; r < 2048; ++r) {
    float4 R = refs[r];  // uniform per wave -> scalar load
    float d = fmaf(R.x, mx, fmaf(R.y, my, fmaf(R.z, mz, R.w + qq)));
    d = fmaxf(d, 0.f);
    float f = __uint_as_float((__float_as_uint(d) & 0xFFFFE000u) | (unsigned)(rbase + r));
    if (f < arr[31]) insert32(arr, f);
  }
#pragma unroll
  for (int i = 0; i < 32; ++i) lbuf[tid][i] = arr[i];
  __syncthreads();
  if (tid < 64) {  // merge 4 chunks for query tid
    for (int c = 1; c < 4; ++c)
      for (int i = 0; i < 32; ++i) {
        float f = lbuf[c * 64 + tid][i];
        if (f < arr[31]) insert32(arr, f);
      }
    int base = (b * NS + tile * 64 + tid) * NK;
#pragma unroll
    for (int i = 0; i < 32; ++i) knn[base + i] = (int)(__float_as_uint(arr[i]) & 0x1FFFu);
  }
}

// ---------------- MLP passes (recompute; BN needs global stats) -------------
// STAGE 0: y0 stats | 1: ->y1 stats | 2: ->y2 stats | 3: full + maxK + out
template <int STAGE>
__global__ __launch_bounds__(256) void mlp_kernel(
    const float4* __restrict__ xyz4, const float4* __restrict__ pts4,
    const float4* __restrict__ nxyz4, const int* __restrict__ knn,
    const float* __restrict__ w0, const float* __restrict__ w1,
    const float* __restrict__ w2, const float* __restrict__ ab,
    float* __restrict__ partials, float* __restrict__ out_np) {
  constexpr int C = (STAGE == 2) ? 64 : 32;              // stats channels
  constexpr int SM = (STAGE == 3) ? 8 * 64 * 32 : 512;   // floats
  __shared__ float smem[SM];
  int blk = blockIdx.x;
  int b = blk >> 6, s0 = (blk & 63) * 32;
  int tid = threadIdx.x, sl = tid & 31, ksec = tid >> 5;
  int lane = tid & 63, wid = tid >> 6;
  int s = s0 + sl;
  float4 Q = nxyz4[b * NS + s];
  const float4* xb = xyz4 + b * NN;
  const float4* pb = pts4 + b * NN;
  const int* kb = knn + (b * NS + s) * NK + ksec * 4;

  float acc1[(STAGE == 3) ? 64 : C];
  float acc2[(STAGE == 3) ? 1 : C];
  if constexpr (STAGE == 3) {
#pragma unroll
    for (int o = 0; o < 64; ++o) acc1[o] = -3.4e38f;
  } else {
#pragma unroll
    for (int o = 0; o < C; ++o) { acc1[o] = 0.f; acc2[o] = 0.f; }
  }

  for (int kk = 0; kk < 4; ++kk) {
    int nid = kb[kk];
    float4 R = xb[nid];
    float4 P = pb[nid];
    float x0[6] = {R.x - Q.x, R.y - Q.y, R.z - Q.z, P.x, P.y, P.z};
    float h[32];
#pragma unroll
    for (int o = 0; o < 32; ++o) {
      float a = w0[o * 6] * x0[0];
#pragma unroll
      for (int c = 1; c < 6; ++c) a = fmaf(w0[o * 6 + c], x0[c], a);
      h[o] = a;
    }
    if constexpr (STAGE == 0) {
#pragma unroll
      for (int o = 0; o < 32; ++o) { acc1[o] += h[o]; acc2[o] = fmaf(h[o], h[o], acc2[o]); }
    } else {
#pragma unroll
      for (int o = 0; o < 32; ++o) h[o] = fmaxf(fmaf(h[o], ab[o], ab[64 + o]), 0.f);
      float h1[32];
#pragma unroll
      for (int o = 0; o < 32; ++o) {
        float a = 0.f;
#pragma unroll
        for (int i = 0; i < 32; ++i) a = fmaf(w1[o * 32 + i], h[i], a);
        h1[o] = a;
      }
      if constexpr (STAGE == 1) {
#pragma unroll
        for (int o = 0; o < 32; ++o) { acc1[o] += h1[o]; acc2[o] = fmaf(h1[o], h1[o], acc2[o]); }
      } else {
#pragma unroll
        for (int o = 0; o < 32; ++o) h1[o] = fmaxf(fmaf(h1[o], ab[128 + o], ab[192 + o]), 0.f);
#pragma unroll
        for (int o = 0; o < 64; ++o) {
          float a = 0.f;
#pragma unroll
          for (int i = 0; i < 32; ++i) a = fmaf(w2[o * 32 + i], h1[i], a);
          if constexpr (STAGE == 2) {
            acc1[o] += a;
            acc2[o] = fmaf(a, a, acc2[o]);
          } else {
            acc1[o] = fmaxf(acc1[o], fmaxf(fmaf(a, ab[256 + o], ab[320 + o]), 0.f));
          }
        }
      }
    }
  }

  if constexpr (STAGE < 3) {
    // wave shuffle reduce -> per-wave slot -> per-block partial
#pragma unroll
    for (int o = 0; o < C; ++o) {
      float v1 = acc1[o], v2 = acc2[o];
#pragma unroll
      for (int d = 1; d < 64; d <<= 1) { v1 += __shfl_xor(v1, d); v2 += __shfl_xor(v2, d); }
      acc1[o] = v1; acc2[o] = v2;
    }
    if (lane == 0) {
#pragma unroll
      for (int o = 0; o < C; ++o) {
        smem[wid * 2 * C + o] = acc1[o];
        smem[wid * 2 * C + C + o] = acc2[o];
      }
    }
    __syncthreads();
    if (tid < 2 * C) {
      float v = smem[tid] + smem[2 * C + tid] + smem[4 * C + tid] + smem[6 * C + tid];
      partials[blk * 128 + tid] = v;
    }
  } else {
#pragma unroll
    for (int o = 0; o < 64; ++o) smem[ksec * 2048 + o * 32 + sl] = acc1[o];
    __syncthreads();
#pragma unroll
    for (int i = 0; i < 8; ++i) {
      int e = i * 256 + tid;
      int ch = e >> 5, ss = e & 31;
      float v = smem[ch * 32 + ss];
#pragma unroll
      for (int ks = 1; ks < 8; ++ks) v = fmaxf(v, smem[ks * 2048 + ch * 32 + ss]);
      out_np[b * 64 * NS + ch * NS + s0 + ss] = v;
    }
  }
}

__global__ __launch_bounds__(256) void finalize_kernel(const float* __restrict__ partials,
                                                       const float* __restrict__ g,
                                                       const float* __restrict__ bt,
                                                       float* __restrict__ ab, int C) {
  __shared__ float sm[256];
  int tid = threadIdx.x;
  int ch = tid & 127, half = tid >> 7;
  float acc = 0.f;
  if (ch < 2 * C) {
    const float* p = partials + half * 256 * 128 + ch;
    for (int i = 0; i < 256; ++i) acc += p[i * 128];
  }
  sm[half * 128 + ch] = acc;
  __syncthreads();
  if (tid < C) {
    float s1 = sm[tid] + sm[128 + tid];
    float s2 = sm[C + tid] + sm[128 + C + tid];
    const float ninv = 1.0f / 524288.0f;  // B*S*K
    float mean = s1 * ninv;
    float var = s2 * ninv - mean * mean;
    float inv = 1.0f / sqrtf(var + 1e-5f);
    float a = g[tid] * inv;
    ab[tid] = a;
    ab[64 + tid] = bt[tid] - mean * a;
  }
}

// ---------------------------------------------------------------------------
extern "C" void kernel_launch(void* const* d_in, const int* in_sizes, int n_in,
                              void* d_out, int out_size, void* d_ws, size_t ws_size,
                              hipStream_t stream) {
  const float* xyz = (const float*)d_in[0];
  const float* pts = (const float*)d_in[1];
  const float* w0 = (const float*)d_in[2];
  const float* g0 = (const float*)d_in[3];
  const float* b0 = (const float*)d_in[4];
  const float* w1 = (const float*)d_in[5];
  const float* g1 = (const float*)d_in[6];
  const float* b1 = (const float*)d_in[7];
  const float* w2 = (const float*)d_in[8];
  const float* g2 = (const float*)d_in[9];
  const float* b2 = (const float*)d_in[10];
  float* out = (float*)d_out;
  float* ws = (float*)d_ws;

  float4* xyz4 = (float4*)ws;                  // 262144 floats
  float4* pts4 = (float4*)(ws + 262144);       // 262144
  float4* nxyz4 = (float4*)(ws + 524288);      // 65536
  int* knn = (int*)(ws + 589824);              // 524288 ints
  float* partials = ws + 1114112;              // 3 * 65536
  float* ab = ws + 1310720;                    // 384
  float* out_np = out + 49152;                 // new_points [8,64,2048]
  float* out_fps = out + 1097728;              // fps_idx as float [8,2048]

  prep_kernel<<<256, 256, 0, stream>>>(xyz, pts, xyz4, pts4);
  fps_kernel<<<NB, 256, 0, stream>>>(xyz4, out, out_fps, nxyz4);
  knn_kernel<<<256, 256, 0, stream>>>(xyz4, nxyz4, knn);

  mlp_kernel<0><<<512, 256, 0, stream>>>(xyz4, pts4, nxyz4, knn, w0, w1, w2, ab, partials, nullptr);
  finalize_kernel<<<1, 256, 0, stream>>>(partials, g0, b0, ab, 32);
  mlp_kernel<1><<<512, 256, 0, stream>>>(xyz4, pts4, nxyz4, knn, w0, w1, w2, ab, partials + 65536, nullptr);
  finalize_kernel<<<1, 256, 0, stream>>>(partials + 65536, g1, b1, ab + 128, 32);
  mlp_kernel<2><<<512, 256, 0, stream>>>(xyz4, pts4, nxyz4, knn, w0, w1, w2, ab, partials + 131072, nullptr);
  finalize_kernel<<<1, 256, 0, stream>>>(partials + 131072, g2, b2, ab + 256, 64);
  mlp_kernel<3><<<512, 256, 0, stream>>>(xyz4, pts4, nxyz4, knn, w0, w1, w2, ab, nullptr, out_np);
}

// Round 3
// 3064.030 us; speedup vs baseline: 1.3519x; 1.0070x over previous
//
#include <hip/hip_runtime.h>
#include <hip/hip_bf16.h>
#include <math.h>

// ---------------------------------------------------------------------------
// PointNet++ Set Abstraction: FPS -> kNN -> grouped MLP(6->32->32->64) with
// BatchNorm(training stats) + ReLU -> max over K.
// B=8, N=8192, S=2048, K=32. All fp32.
//
// d_out layout (floats): new_xyz [8,3,2048] | new_points [8,64,2048] | fps_idx [8,2048]
// ---------------------------------------------------------------------------

#define NB 8
#define NN 8192
#define NS 2048
#define NK 32

// ---------------- prep: transpose to [B,N,4] with w = |p|^2 -----------------
__global__ __launch_bounds__(256) void prep_kernel(const float* __restrict__ xyz,
                                                   const float* __restrict__ pts,
                                                   float4* __restrict__ xyz4,
                                                   float4* __restrict__ pts4) {
  int g = blockIdx.x * 256 + threadIdx.x;      // 65536 = B*N
  int b = g >> 13, n = g & 8191;
  const float* xb = xyz + b * 3 * NN;
  float x = xb[n], y = xb[NN + n], z = xb[2 * NN + n];
  xyz4[g] = make_float4(x, y, z, fmaf(x, x, fmaf(y, y, z * z)));
  const float* pb = pts + b * 3 * NN;
  pts4[g] = make_float4(pb[n], pb[NN + n], pb[2 * NN + n], 0.f);
}

// ---------------- FPS: one block/batch, DPP wave-reduce, 1 barrier/iter -----
template <int CTRL>
__device__ __forceinline__ float dpp_max(float v) {
  int o = __builtin_amdgcn_update_dpp(__float_as_int(v), __float_as_int(v),
                                      CTRL, 0xf, 0xf, false);
  return fmaxf(v, __int_as_float(o));
}

__global__ __launch_bounds__(256, 1) void fps_kernel(const float4* __restrict__ xyz4,
                                                     float* __restrict__ out_nxyz,
                                                     float* __restrict__ out_fps,
                                                     float4* __restrict__ nxyz4) {
  int b = blockIdx.x, tid = threadIdx.x;
  int lane = tid & 63, wid = tid >> 6;
  __shared__ unsigned long long wslot[2][4];
  const float4* xb = xyz4 + b * NN;

  // thread owns contiguous points [tid*32, tid*32+32): lane order == gid order
  float px[32], py[32], pz[32], dist[32];
#pragma unroll
  for (int j = 0; j < 32; ++j) {
    float4 t = xb[(tid << 5) + j];
    px[j] = t.x; py[j] = t.y; pz[j] = t.z;
    dist[j] = 1e10f;
  }
  // Pin coords in VGPRs: opaque asm def prevents the compiler from
  // rematerializing the global loads inside the 2047-iteration serial loop
  // (R1 profile: VGPR_Count=76 -> coords were re-loaded from L2 every iter,
  //  128KB/CU/iter = 0.95us/iter, exactly the measured time).
#pragma unroll
  for (int j = 0; j < 32; ++j) {
    asm volatile("" : "+v"(px[j]), "+v"(py[j]), "+v"(pz[j]));
  }

  float4 c0 = xb[0];
  float cx = c0.x, cy = c0.y, cz = c0.z;
  if (tid == 0) {
    nxyz4[b * NS] = c0;
    out_nxyz[b * 3 * NS] = c0.x;
    out_nxyz[b * 3 * NS + NS] = c0.y;
    out_nxyz[b * 3 * NS + 2 * NS] = c0.z;
    out_fps[b * NS] = 0.f;
  }

  for (int s = 1; s < NS; ++s) {
    // exact (no-FMA, left-to-right) distance, running min, fused argmax track
    float best = -1.0f;
    int bj = 0;
#pragma unroll
    for (int j = 0; j < 32; ++j) {
      float dx = __fsub_rn(px[j], cx);
      float dy = __fsub_rn(py[j], cy);
      float dz = __fsub_rn(pz[j], cz);
      float d = __fadd_rn(__fadd_rn(__fmul_rn(dx, dx), __fmul_rn(dy, dy)),
                          __fmul_rn(dz, dz));
      d = fminf(dist[j], d);
      dist[j] = d;
      bool gt = d > best;           // strict >: keeps smallest j on ties
      best = gt ? d : best;
      bj = gt ? j : bj;
    }

    // wave64 max via DPP (all VALU, no LDS): result valid in lane 63
    float m = best;
    m = dpp_max<0x111>(m);  // row_shr:1
    m = dpp_max<0x112>(m);  // row_shr:2
    m = dpp_max<0x114>(m);  // row_shr:4
    m = dpp_max<0x118>(m);  // row_shr:8
    m = dpp_max<0x142>(m);  // row_bcast:15
    m = dpp_max<0x143>(m);  // row_bcast:31
    float wmax = __int_as_float(__builtin_amdgcn_readlane(__float_as_int(m), 63));

    unsigned long long bl = __ballot(best == wmax);
    int l0 = __ffsll((unsigned long long)bl) - 1;   // lowest lane = lowest gid
    int gcand = (tid << 5) + bj;
    int gw = __builtin_amdgcn_readlane(gcand, l0);

    if (lane == 0)
      wslot[s & 1][wid] = (((unsigned long long)__float_as_uint(wmax)) << 32) |
                          (unsigned)(8191 - gw);  // u64-max => max val, min gid
    __syncthreads();

    unsigned long long v0 = wslot[s & 1][0], v1 = wslot[s & 1][1];
    unsigned long long v2 = wslot[s & 1][2], v3 = wslot[s & 1][3];
    unsigned long long va = v0 > v1 ? v0 : v1;
    unsigned long long vb = v2 > v3 ? v2 : v3;
    unsigned long long vm = va > vb ? va : vb;
    int gid = 8191 - (int)(unsigned)(vm & 0xFFFFFFFFull);
    gid = __builtin_amdgcn_readfirstlane(gid);  // uniform -> scalar load path

    float4 c = xb[gid];  // s_load / single broadcast request (L2-resident)
    cx = c.x; cy = c.y; cz = c.z;
    if (tid == 0) {
      nxyz4[b * NS + s] = c;
      out_nxyz[b * 3 * NS + s] = c.x;
      out_nxyz[b * 3 * NS + NS + s] = c.y;
      out_nxyz[b * 3 * NS + 2 * NS + s] = c.z;
      out_fps[b * NS + s] = (float)gid;
    }
    // no second barrier: parity buffer wslot[s&1]; iter s+2's write can only
    // happen after barrier s+1, which requires all threads done reading iter s
  }
}

// ---------------- kNN: idx packed into low 13 mantissa bits -----------------
__device__ __forceinline__ void insert32(float (&a)[32], float f) {
  // sorted ascending; keep 32 smallest. new[i] = min(a[i], max(a[i-1], f))
#pragma unroll
  for (int i = 31; i >= 1; --i) a[i] = fminf(a[i], fmaxf(a[i - 1], f));
  a[0] = fminf(a[0], f);
}

__global__ __launch_bounds__(256) void knn_kernel(const float4* __restrict__ xyz4,
                                                  const float4* __restrict__ nxyz4,
                                                  int* __restrict__ knn) {
  __shared__ float lbuf[256][33];  // +1 pad: conflict-free
  int b = blockIdx.x >> 5, tile = blockIdx.x & 31;
  int tid = threadIdx.x;
  int q = tid & 63, chunk = tid >> 6;  // 64 queries x 4 ref-chunks
  float4 Q = nxyz4[b * NS + tile * 64 + q];
  float qq = Q.w;
  float mx = -2.f * Q.x, my = -2.f * Q.y, mz = -2.f * Q.z;
  float arr[32];
#pragma unroll
  for (int i = 0; i < 32; ++i) arr[i] = __uint_as_float(0x7f7fffffu);

  const float4* refs = xyz4 + b * NN + chunk * 2048;
  int rbase = chunk * 2048;
  for (int r = 0; r < 2048; ++r) {
    float4 R = refs[r];  // uniform per wave -> scalar load
    float d = fmaf(R.x, mx, fmaf(R.y, my, fmaf(R.z, mz, R.w + qq)));
    d = fmaxf(d, 0.f);
    float f = __uint_as_float((__float_as_uint(d) & 0xFFFFE000u) | (unsigned)(rbase + r));
    if (f < arr[31]) insert32(arr, f);
  }
#pragma unroll
  for (int i = 0; i < 32; ++i) lbuf[tid][i] = arr[i];
  __syncthreads();
  if (tid < 64) {  // merge 4 chunks for query tid
    for (int c = 1; c < 4; ++c)
      for (int i = 0; i < 32; ++i) {
        float f = lbuf[c * 64 + tid][i];
        if (f < arr[31]) insert32(arr, f);
      }
    int base = (b * NS + tile * 64 + tid) * NK;
#pragma unroll
    for (int i = 0; i < 32; ++i) knn[base + i] = (int)(__float_as_uint(arr[i]) & 0x1FFFu);
  }
}

// ---------------- MLP passes (recompute; BN needs global stats) -------------
// STAGE 0: y0 stats | 1: ->y1 stats | 2: ->y2 stats | 3: full + maxK + out
template <int STAGE>
__global__ __launch_bounds__(256) void mlp_kernel(
    const float4* __restrict__ xyz4, const float4* __restrict__ pts4,
    const float4* __restrict__ nxyz4, const int* __restrict__ knn,
    const float* __restrict__ w0, const float* __restrict__ w1,
    const float* __restrict__ w2, const float* __restrict__ ab,
    float* __restrict__ partials, float* __restrict__ out_np) {
  constexpr int C = (STAGE == 2) ? 64 : 32;              // stats channels
  constexpr int SM = (STAGE == 3) ? 8 * 64 * 32 : 512;   // floats
  __shared__ float smem[SM];
  int blk = blockIdx.x;
  int b = blk >> 6, s0 = (blk & 63) * 32;
  int tid = threadIdx.x, sl = tid & 31, ksec = tid >> 5;
  int lane = tid & 63, wid = tid >> 6;
  int s = s0 + sl;
  float4 Q = nxyz4[b * NS + s];
  const float4* xb = xyz4 + b * NN;
  const float4* pb = pts4 + b * NN;
  const int* kb = knn + (b * NS + s) * NK + ksec * 4;

  float acc1[(STAGE == 3) ? 64 : C];
  float acc2[(STAGE == 3) ? 1 : C];
  if constexpr (STAGE == 3) {
#pragma unroll
    for (int o = 0; o < 64; ++o) acc1[o] = -3.4e38f;
  } else {
#pragma unroll
    for (int o = 0; o < C; ++o) { acc1[o] = 0.f; acc2[o] = 0.f; }
  }

  for (int kk = 0; kk < 4; ++kk) {
    int nid = kb[kk];
    float4 R = xb[nid];
    float4 P = pb[nid];
    float x0[6] = {R.x - Q.x, R.y - Q.y, R.z - Q.z, P.x, P.y, P.z};
    float h[32];
#pragma unroll
    for (int o = 0; o < 32; ++o) {
      float a = w0[o * 6] * x0[0];
#pragma unroll
      for (int c = 1; c < 6; ++c) a = fmaf(w0[o * 6 + c], x0[c], a);
      h[o] = a;
    }
    if constexpr (STAGE == 0) {
#pragma unroll
      for (int o = 0; o < 32; ++o) { acc1[o] += h[o]; acc2[o] = fmaf(h[o], h[o], acc2[o]); }
    } else {
#pragma unroll
      for (int o = 0; o < 32; ++o) h[o] = fmaxf(fmaf(h[o], ab[o], ab[64 + o]), 0.f);
      float h1[32];
#pragma unroll
      for (int o = 0; o < 32; ++o) {
        float a = 0.f;
#pragma unroll
        for (int i = 0; i < 32; ++i) a = fmaf(w1[o * 32 + i], h[i], a);
        h1[o] = a;
      }
      if constexpr (STAGE == 1) {
#pragma unroll
        for (int o = 0; o < 32; ++o) { acc1[o] += h1[o]; acc2[o] = fmaf(h1[o], h1[o], acc2[o]); }
      } else {
#pragma unroll
        for (int o = 0; o < 32; ++o) h1[o] = fmaxf(fmaf(h1[o], ab[128 + o], ab[192 + o]), 0.f);
#pragma unroll
        for (int o = 0; o < 64; ++o) {
          float a = 0.f;
#pragma unroll
          for (int i = 0; i < 32; ++i) a = fmaf(w2[o * 32 + i], h1[i], a);
          if constexpr (STAGE == 2) {
            acc1[o] += a;
            acc2[o] = fmaf(a, a, acc2[o]);
          } else {
            acc1[o] = fmaxf(acc1[o], fmaxf(fmaf(a, ab[256 + o], ab[320 + o]), 0.f));
          }
        }
      }
    }
  }

  if constexpr (STAGE < 3) {
    // wave shuffle reduce -> per-wave slot -> per-block partial
#pragma unroll
    for (int o = 0; o < C; ++o) {
      float v1 = acc1[o], v2 = acc2[o];
#pragma unroll
      for (int d = 1; d < 64; d <<= 1) { v1 += __shfl_xor(v1, d); v2 += __shfl_xor(v2, d); }
      acc1[o] = v1; acc2[o] = v2;
    }
    if (lane == 0) {
#pragma unroll
      for (int o = 0; o < C; ++o) {
        smem[wid * 2 * C + o] = acc1[o];
        smem[wid * 2 * C + C + o] = acc2[o];
      }
    }
    __syncthreads();
    if (tid < 2 * C) {
      float v = smem[tid] + smem[2 * C + tid] + smem[4 * C + tid] + smem[6 * C + tid];
      partials[blk * 128 + tid] = v;
    }
  } else {
#pragma unroll
    for (int o = 0; o < 64; ++o) smem[ksec * 2048 + o * 32 + sl] = acc1[o];
    __syncthreads();
#pragma unroll
    for (int i = 0; i < 8; ++i) {
      int e = i * 256 + tid;
      int ch = e >> 5, ss = e & 31;
      float v = smem[ch * 32 + ss];
#pragma unroll
      for (int ks = 1; ks < 8; ++ks) v = fmaxf(v, smem[ks * 2048 + ch * 32 + ss]);
      out_np[b * 64 * NS + ch * NS + s0 + ss] = v;
    }
  }
}

__global__ __launch_bounds__(256) void finalize_kernel(const float* __restrict__ partials,
                                                       const float* __restrict__ g,
                                                       const float* __restrict__ bt,
                                                       float* __restrict__ ab, int C) {
  __shared__ float sm[256];
  int tid = threadIdx.x;
  int ch = tid & 127, half = tid >> 7;
  float acc = 0.f;
  if (ch < 2 * C) {
    const float* p = partials + half * 256 * 128 + ch;
    for (int i = 0; i < 256; ++i) acc += p[i * 128];
  }
  sm[half * 128 + ch] = acc;
  __syncthreads();
  if (tid < C) {
    float s1 = sm[tid] + sm[128 + tid];
    float s2 = sm[C + tid] + sm[128 + C + tid];
    const float ninv = 1.0f / 524288.0f;  // B*S*K
    float mean = s1 * ninv;
    float var = s2 * ninv - mean * mean;
    float inv = 1.0f / sqrtf(var + 1e-5f);
    float a = g[tid] * inv;
    ab[tid] = a;
    ab[64 + tid] = bt[tid] - mean * a;
  }
}

// ---------------------------------------------------------------------------
extern "C" void kernel_launch(void* const* d_in, const int* in_sizes, int n_in,
                              void* d_out, int out_size, void* d_ws, size_t ws_size,
                              hipStream_t stream) {
  const float* xyz = (const float*)d_in[0];
  const float* pts = (const float*)d_in[1];
  const float* w0 = (const float*)d_in[2];
  const float* g0 = (const float*)d_in[3];
  const float* b0 = (const float*)d_in[4];
  const float* w1 = (const float*)d_in[5];
  const float* g1 = (const float*)d_in[6];
  const float* b1 = (const float*)d_in[7];
  const float* w2 = (const float*)d_in[8];
  const float* g2 = (const float*)d_in[9];
  const float* b2 = (const float*)d_in[10];
  float* out = (float*)d_out;
  float* ws = (float*)d_ws;

  float4* xyz4 = (float4*)ws;                  // 262144 floats
  float4* pts4 = (float4*)(ws + 262144);       // 262144
  float4* nxyz4 = (float4*)(ws + 524288);      // 65536
  int* knn = (int*)(ws + 589824);              // 524288 ints
  float* partials = ws + 1114112;              // 3 * 65536
  float* ab = ws + 1310720;                    // 384
  float* out_np = out + 49152;                 // new_points [8,64,2048]
  float* out_fps = out + 1097728;              // fps_idx as float [8,2048]

  prep_kernel<<<256, 256, 0, stream>>>(xyz, pts, xyz4, pts4);
  fps_kernel<<<NB, 256, 0, stream>>>(xyz4, out, out_fps, nxyz4);
  knn_kernel<<<256, 256, 0, stream>>>(xyz4, nxyz4, knn);

  mlp_kernel<0><<<512, 256, 0, stream>>>(xyz4, pts4, nxyz4, knn, w0, w1, w2, ab, partials, nullptr);
  finalize_kernel<<<1, 256, 0, stream>>>(partials, g0, b0, ab, 32);
  mlp_kernel<1><<<512, 256, 0, stream>>>(xyz4, pts4, nxyz4, knn, w0, w1, w2, ab, partials + 65536, nullptr);
  finalize_kernel<<<1, 256, 0, stream>>>(partials + 65536, g1, b1, ab + 128, 32);
  mlp_kernel<2><<<512, 256, 0, stream>>>(xyz4, pts4, nxyz4, knn, w0, w1, w2, ab, partials + 131072, nullptr);
  finalize_kernel<<<1, 256, 0, stream>>>(partials + 131072, g2, b2, ab + 256, 64);
  mlp_kernel<3><<<512, 256, 0, stream>>>(xyz4, pts4, nxyz4, knn, w0, w1, w2, ab, nullptr, out_np);
}